// Round 5
// baseline (68.793 us; speedup 1.0000x reference)
//
#include <hip/hip_runtime.h>

// AffinitySideLoss: B=4, E=12, H=W=512, S=8 offsets, output = 1 float scalar.
// d_in[0] = input_ float32 [4,12,512,512]
// d_in[1] = target int32   [4,1,512,512]
// d_in[2] = offsets int32  [8,2]  (values in [-27,0))
// d_out   = float32 [1]
// d_ws    = per-block partials: float [16][2048]  (131,072 B)
//
// Decomposition: one block per image row (2048 blocks). 128 threads x 4 px
// (float4): w4 = tid*4 in {0..508}. b = nb>>9, h = nb&511 are block-uniform;
// offsets are read at uniform addresses (s_load) so shifted-load addresses
// are SGPR-base + one small VGPR offset -> global_load_dwordx4.

typedef float f4  __attribute__((ext_vector_type(4)));
typedef float f4u __attribute__((ext_vector_type(4), aligned(4)));
typedef int   i4  __attribute__((ext_vector_type(4)));
typedef int   i4u __attribute__((ext_vector_type(4), aligned(4)));

#define HWSZ 262144   // 512*512
#define NE   12
#define NS   8
#define NBLK 2048     // 4 batches x 512 rows

__global__ __launch_bounds__(128) void affloss_main(
    const float* __restrict__ emb, const int* __restrict__ seg,
    const int* __restrict__ offs, float* __restrict__ partial) {
  // XCD-aware swizzle (bijective: 2048 % 8 == 0): contiguous 256-row band
  // per XCD so shifted rows (<=27 above) hit that XCD's L2.
  const int bid = blockIdx.x;
  const int nb  = (bid & 7) * (NBLK / 8) + (bid >> 3);

  const int h  = nb & 511;         // row, block-uniform
  const int b  = nb >> 9;          // batch 0..3, block-uniform
  const int w4 = threadIdx.x << 2; // 0..508

  const float* embB = emb + (size_t)b * NE * HWSZ;
  const int*   segB = seg + (size_t)b * HWSZ;
  const int base = (h << 9) + w4;

  // center embedding: 12 x float4 (16B aligned)
  f4 c[NE];
  #pragma unroll
  for (int e = 0; e < NE; ++e)
    c[e] = *reinterpret_cast<const f4*>(embB + e * HWSZ + base);
  const i4 tc = *reinterpret_cast<const i4*>(segB + base);

  float num[NS], den[NS];
  #pragma unroll
  for (int s = 0; s < NS; ++s) { num[s] = 0.f; den[s] = 0.f; }

  #pragma unroll
  for (int s = 0; s < NS; ++s) {
    // uniform-address loads -> scalar (s_load); oy,ox in [-27,-1]
    const int oy = offs[2 * s];
    const int ox = offs[2 * s + 1];
    int hs = h + oy; hs = hs < 0 ? 0 : hs;   // replication clamp (top only)
    const int rowoff = hs << 9;
    const int wsb = w4 + ox;                 // >= -27, <= 507 (upper edge safe)

    f4 ssv = {0.f, 0.f, 0.f, 0.f};
    i4 ts;
    if (wsb >= 0) {
      // interior: contiguous 16B loads at 4B alignment (single dwordx4)
      #pragma unroll
      for (int e = 0; e < NE; ++e) {
        f4 sh = *reinterpret_cast<const f4u*>(embB + e * HWSZ + rowoff + wsb);
        f4 d = c[e] - sh;
        ssv += d * d;
      }
      ts = *reinterpret_cast<const i4u*>(segB + rowoff + wsb);
    } else {
      // left-edge replication clamp; only tid < 7 can land here
      int w0 = max(wsb, 0), w1 = max(wsb + 1, 0);
      int w2 = max(wsb + 2, 0), w3 = max(wsb + 3, 0);
      #pragma unroll
      for (int e = 0; e < NE; ++e) {
        const float* p = embB + e * HWSZ + rowoff;
        f4 sh = { p[w0], p[w1], p[w2], p[w3] };
        f4 d = c[e] - sh;
        ssv += d * d;
      }
      const int* ps = segB + rowoff;
      ts[0] = ps[w0]; ts[1] = ps[w1]; ts[2] = ps[w2]; ts[3] = ps[w3];
    }

    #pragma unroll
    for (int j = 0; j < 4; ++j) {
      float ss = ssv[j];                       // >= 0 by construction
      float n  = __builtin_amdgcn_sqrtf(ss);   // v_sqrt_f32; sqrt(0)=0 covers where()
      float r  = fmaxf(fmaf(n, -(1.0f / 3.0f), 1.0f), 0.0f); // clip((3-n)/3, 0)
      float a  = fmaf(-r, r, 1.0f);            // affinity = 1 - r^2
      float ta = (tc[j] == ts[j]) ? 0.f : 1.f; // 1 - equality
      num[s] = fmaf(a, ta, num[s]);
      den[s] += fmaf(a, a, ta);                // a^2 + ta  (ta^2 == ta)
    }
  }

  // pack: [0..7]=num, [8..15]=den
  float arr[16];
  #pragma unroll
  for (int s = 0; s < NS; ++s) { arr[s] = num[s]; arr[8 + s] = den[s]; }

  // wave (64-lane) shuffle reduction per channel
  #pragma unroll
  for (int k = 0; k < 16; ++k) {
    float v = arr[k];
    #pragma unroll
    for (int o = 32; o > 0; o >>= 1) v += __shfl_down(v, o, 64);
    arr[k] = v;
  }

  __shared__ float red[2][16];
  const int lane = threadIdx.x & 63, wv = threadIdx.x >> 6;
  if (lane == 0) {
    #pragma unroll
    for (int k = 0; k < 16; ++k) red[wv][k] = arr[k];
  }
  __syncthreads();
  if (threadIdx.x < 16) {
    float v = red[0][threadIdx.x] + red[1][threadIdx.x];
    partial[threadIdx.x * NBLK + blockIdx.x] = v;  // [channel][block]
  }
}

__global__ __launch_bounds__(1024) void affloss_final(
    const float* __restrict__ partial, float* __restrict__ out) {
  __shared__ double csum[16];
  const int lane = threadIdx.x & 63, wv = threadIdx.x >> 6;  // wv = channel 0..15

  double s = 0.0;
  for (int i = lane; i < NBLK; i += 64)
    s += (double)partial[wv * NBLK + i];
  #pragma unroll
  for (int o = 32; o > 0; o >>= 1) s += __shfl_down(s, o, 64);
  if (lane == 0) csum[wv] = s;
  __syncthreads();

  if (threadIdx.x == 0) {
    double total = 0.0;
    #pragma unroll
    for (int c = 0; c < 8; ++c) {
      double num = csum[c];
      double den = csum[8 + c];
      if (den < 1e-7) den = 1e-7;              // maximum(den, EPS)
      total += 1.0 - 2.0 * num / den;
    }
    out[0] = (float)total;
  }
}

extern "C" void kernel_launch(void* const* d_in, const int* in_sizes, int n_in,
                              void* d_out, int out_size, void* d_ws, size_t ws_size,
                              hipStream_t stream) {
  const float* emb  = (const float*)d_in[0];
  const int*   seg  = (const int*)d_in[1];
  const int*   offs = (const int*)d_in[2];
  float* partial = (float*)d_ws;   // 16*2048 floats = 131,072 B

  affloss_main<<<NBLK, 128, 0, stream>>>(emb, seg, offs, partial);
  affloss_final<<<1, 1024, 0, stream>>>(partial, (float*)d_out);
}

// Round 6
// 51.334 us; speedup vs baseline: 1.3401x; 1.3401x over previous
//
#include <hip/hip_runtime.h>

// AffinitySideLoss: B=4, E=12, H=W=512, S=8 offsets, output = 1 float scalar.
// d_in[0] = input_ float32 [4,12,512,512]
// d_in[1] = target int32   [4,1,512,512]
// d_in[2] = offsets int32  [8,2]  (values in [-27,0))
// d_out   = float32 [1]
// d_ws    = per-block partials: float [16][2048]  (131,072 B)
//
// R6: one block per image row (proven R4 indexing) + LDS double-buffered
// staging of shifted emb rows via global_load_lds (width 16). In-flight
// staging bytes live in LDS, not VGPRs -> deep memory pipeline while
// keeping the 64-VGPR / high-wave regime. 48 KB LDS -> 3 blocks/CU; the
// per-block barrier drain is hidden by cross-block overlap.

typedef float f2  __attribute__((ext_vector_type(2)));
typedef int   i2  __attribute__((ext_vector_type(2)));
typedef int   i2u __attribute__((ext_vector_type(2), aligned(4)));

#define HWSZ 262144   // 512*512
#define NE   12
#define NS   8
#define NBLK 2048     // 4 batches x 512 rows

typedef const __attribute__((address_space(1))) void* gas_t;
typedef __attribute__((address_space(3))) void* las_t;

__global__ __launch_bounds__(256) void affloss_main(
    const float* __restrict__ emb, const int* __restrict__ seg,
    const int* __restrict__ offs, float* __restrict__ partial) {
  __shared__ float lbuf[2][NE * 512];   // 2 x 24576 B = 49152 B

  // XCD-aware swizzle (bijective: 2048 % 8 == 0): contiguous 256-row band
  // per XCD so shifted rows (<=27 above) hit that XCD's L2.
  const int bid = blockIdx.x;
  const int nb  = (bid & 7) * (NBLK / 8) + (bid >> 3);

  const int h    = nb & 511;        // row, block-uniform
  const int b    = nb >> 9;         // batch 0..3, block-uniform
  const int tid  = threadIdx.x;
  const int w2   = tid << 1;        // 0..510
  const int wv   = tid >> 6;        // wave id 0..3 (wave-uniform)

  const float* embB = emb + (size_t)b * NE * HWSZ;
  const int*   segB = seg + (size_t)b * HWSZ;

  // Stage the full shifted emb row (12 ch x 512 cols) for offset s into
  // lbuf[bi]. 6 issues x (256 lanes x 16 B) = 24576 B. LDS dest is
  // wave-uniform base + lane*16 (m104): base = k*4096 + wv*1024 bytes.
  auto stage = [&](int bi, int s) {
    const int oy = offs[2 * s];              // s_load, uniform
    int hs = h + oy; hs = hs < 0 ? 0 : hs;   // replication clamp (top)
    const int rowoff = hs << 9;
    #pragma unroll
    for (int k = 0; k < 6; ++k) {
      const int f = k * 1024 + tid * 4;      // flat float index in [12][512]
      const float* src = embB + (f >> 9) * HWSZ + rowoff + (f & 511);
      float* dst = &lbuf[bi][k * 1024 + wv * 256];
      __builtin_amdgcn_global_load_lds((gas_t)src, (las_t)dst, 16, 0, 0);
    }
  };

  // kick off first two tiles before doing anything else
  stage(0, 0);
  stage(1, 1);

  // center embedding: 12 x float2 (8B aligned) + center seg
  const int base = (h << 9) + w2;
  f2 c[NE];
  #pragma unroll
  for (int e = 0; e < NE; ++e)
    c[e] = *reinterpret_cast<const f2*>(embB + e * HWSZ + base);
  const i2 tc = *reinterpret_cast<const i2u*>(segB + base);

  // prefetch ALL shifted seg values (completes under the first stages)
  i2 tsv[NS];
  #pragma unroll
  for (int s = 0; s < NS; ++s) {
    const int oy = offs[2 * s];
    const int ox = offs[2 * s + 1];
    int hs = h + oy; hs = hs < 0 ? 0 : hs;
    const int rowoff = hs << 9;
    const int wsb = w2 + ox;                 // >= -27, <= 509
    if (wsb >= 0) {
      tsv[s] = *reinterpret_cast<const i2u*>(segB + rowoff + wsb);
    } else {
      tsv[s][0] = segB[rowoff + max(wsb, 0)];
      tsv[s][1] = segB[rowoff + max(wsb + 1, 0)];
    }
  }

  float num[NS], den[NS];
  #pragma unroll
  for (int s = 0; s < NS; ++s) { num[s] = 0.f; den[s] = 0.f; }

  #pragma unroll
  for (int s = 0; s < NS; ++s) {
    __syncthreads();                         // drains vmcnt -> lbuf[s&1] ready

    const int ox = offs[2 * s + 1];
    int col0 = w2 + ox;     col0 = col0 < 0 ? 0 : col0;   // replication clamp
    int col1 = w2 + 1 + ox; col1 = col1 < 0 ? 0 : col1;
    const float* bufp = lbuf[s & 1];

    f2 ssv = {0.f, 0.f};
    #pragma unroll
    for (int e = 0; e < NE; ++e) {
      float sh0 = bufp[e * 512 + col0];      // stride-2 lanes: 2-way alias, free
      float sh1 = bufp[e * 512 + col1];
      float d0 = c[e][0] - sh0;
      float d1 = c[e][1] - sh1;
      ssv[0] = fmaf(d0, d0, ssv[0]);
      ssv[1] = fmaf(d1, d1, ssv[1]);
    }

    __syncthreads();                         // all waves done reading lbuf[s&1]
    if (s < NS - 2) stage(s & 1, s + 2);     // overwrite with tile s+2

    // epilogue math after issuing the DMA (head start for the loads)
    #pragma unroll
    for (int j = 0; j < 2; ++j) {
      float ss = ssv[j];                       // >= 0 by construction
      float n  = __builtin_amdgcn_sqrtf(ss);   // sqrt(0)=0 covers the where()
      float r  = fmaxf(fmaf(n, -(1.0f / 3.0f), 1.0f), 0.0f); // clip((3-n)/3, 0)
      float a  = fmaf(-r, r, 1.0f);            // affinity = 1 - r^2
      float ta = (tc[j] == tsv[s][j]) ? 0.f : 1.f;
      num[s] = fmaf(a, ta, num[s]);
      den[s] += fmaf(a, a, ta);                // a^2 + ta  (ta^2 == ta)
    }
  }

  // pack: [0..7]=num, [8..15]=den
  float arr[16];
  #pragma unroll
  for (int s = 0; s < NS; ++s) { arr[s] = num[s]; arr[8 + s] = den[s]; }

  // wave (64-lane) shuffle reduction per channel
  #pragma unroll
  for (int k = 0; k < 16; ++k) {
    float v = arr[k];
    #pragma unroll
    for (int o = 32; o > 0; o >>= 1) v += __shfl_down(v, o, 64);
    arr[k] = v;
  }

  __shared__ float red[4][16];
  const int lane = tid & 63;
  if (lane == 0) {
    #pragma unroll
    for (int k = 0; k < 16; ++k) red[wv][k] = arr[k];
  }
  __syncthreads();
  if (tid < 16) {
    float v = red[0][tid] + red[1][tid] + red[2][tid] + red[3][tid];
    partial[tid * NBLK + blockIdx.x] = v;    // [channel][block]
  }
}

__global__ __launch_bounds__(1024) void affloss_final(
    const float* __restrict__ partial, float* __restrict__ out) {
  __shared__ double csum[16];
  const int lane = threadIdx.x & 63, wv = threadIdx.x >> 6;  // wv = channel 0..15

  double s = 0.0;
  for (int i = lane; i < NBLK; i += 64)
    s += (double)partial[wv * NBLK + i];
  #pragma unroll
  for (int o = 32; o > 0; o >>= 1) s += __shfl_down(s, o, 64);
  if (lane == 0) csum[wv] = s;
  __syncthreads();

  if (threadIdx.x == 0) {
    double total = 0.0;
    #pragma unroll
    for (int c = 0; c < 8; ++c) {
      double num = csum[c];
      double den = csum[8 + c];
      if (den < 1e-7) den = 1e-7;              // maximum(den, EPS)
      total += 1.0 - 2.0 * num / den;
    }
    out[0] = (float)total;
  }
}

extern "C" void kernel_launch(void* const* d_in, const int* in_sizes, int n_in,
                              void* d_out, int out_size, void* d_ws, size_t ws_size,
                              hipStream_t stream) {
  const float* emb  = (const float*)d_in[0];
  const int*   seg  = (const int*)d_in[1];
  const int*   offs = (const int*)d_in[2];
  float* partial = (float*)d_ws;   // 16*2048 floats = 131,072 B

  affloss_main<<<NBLK, 256, 0, stream>>>(emb, seg, offs, partial);
  affloss_final<<<1, 1024, 0, stream>>>(partial, (float*)d_out);
}